// Round 1
// baseline (26.558 us; speedup 1.0000x reference)
//
#include <hip/hip_runtime.h>
#include <hip/hip_bf16.h>

// Problem constants (fixed by the reference)
#define NG   1024
#define IMGW 256
#define IMGH 256
#define NC   64
#define CULL_T 15.0f   // cull when sigma > T; dropped mass <= 1024*2*0.07*e^-15 ~ 4e-5

// ---------------------------------------------------------------------------
// Kernel 1: per-gaussian parameter precompute + softplus(features) into ws.
// blocks 0..255: feats (65536 softplus). block 256: 1024 gaussians, 4/thread.
// ---------------------------------------------------------------------------
__global__ __launch_bounds__(256) void prep_kernel(
    const float* __restrict__ xyz,  const float* __restrict__ chol,
    const float* __restrict__ opac, const float* __restrict__ fdc,
    const float* __restrict__ gfrq, const float* __restrict__ gwts,
    float*  __restrict__ feats, float4* __restrict__ cull,
    float4* __restrict__ coef,  float4* __restrict__ gab,
    float2* __restrict__ wts)
{
    const int b = blockIdx.x, t = threadIdx.x;
    if (b < 256) {
        const int i = (b << 8) + t;
        const float x = fdc[i];
        // softplus, stable both sides (x ~ -2.97 here)
        feats[i] = x > 0.f ? x + log1pf(expf(-x)) : log1pf(expf(x));
        return;
    }
    // parameter block: 4 gaussians per thread, stride-256 for coalescing
    for (int j = 0; j < 4; ++j) {
        const int n = (j << 8) + t;
        const float2 xy = ((const float2*)xyz)[n];
        const float xs = 128.f * (tanhf(xy.x) + 1.f);
        const float ys = 128.f * (tanhf(xy.y) + 1.f);

        const float l1 = chol[3*n]     + 0.5f;
        const float l2 = chol[3*n + 1];
        const float l3 = chol[3*n + 2] + 0.5f;
        const float s11 = l1*l1, s12 = l1*l2, s22 = l2*l2 + l3*l3;
        const float dt  = (l1*l3) * (l1*l3);
        const float ca = s22/dt, cb = -(s12/dt), cc = s11/dt;
        const float mid = 0.5f*(s11 + s22);
        const float lam = mid + sqrtf(fmaxf(mid*mid - dt, 1e-8f));
        const float radius = ceilf(3.f * sqrtf(lam));
        const float keep = (radius > 1.0f) ? 1.f : 0.f;   // RADIUS_CLIP = 1.0
        const float oK = opac[n] * keep;                  // fold opacity*keep
        const float r2 = (oK != 0.f) ? (2.f * CULL_T * lam) : -1.f;

        cull[n] = make_float4(xs, ys, r2, oK);
        coef[n] = make_float4(ca, cb, cc, 0.f);
        const float4 gf = ((const float4*)gfrq)[n];       // (f00,f01,f10,f11) logs
        gab[n]  = make_float4(expf(gf.x), expf(gf.y), expf(gf.z), expf(gf.w));
        const float2 gw = ((const float2*)gwts)[n];
        wts[n]  = make_float2(1.f/(1.f + expf(-gw.x)), 1.f/(1.f + expf(-gw.y)));
    }
}

// ---------------------------------------------------------------------------
// Kernel 2: one block per 32x8 pixel tile. Deterministic ballot-compaction of
// surviving gaussians (ascending id order), then per-pixel accumulation with
// wave-uniform scalar param/feat loads and 64 VGPR accumulators per thread.
// ---------------------------------------------------------------------------
__global__ __launch_bounds__(256) void render_kernel(
    const float*  __restrict__ feats, const float4* __restrict__ cull,
    const float4* __restrict__ coef,  const float4* __restrict__ gab,
    const float2* __restrict__ wts,   float* __restrict__ out)
{
    __shared__ unsigned short s_ids[4][256];
    __shared__ int            s_cnt[4];
    __shared__ unsigned short s_list[NG];

    const int tid  = threadIdx.x;
    const int lane = tid & 63, w = tid >> 6;

    const int x0 = (blockIdx.x & 7) << 5;   // 8 tiles across (32 px wide)
    const int y0 = (blockIdx.x >> 3) << 3;  // 32 tiles down  (8 px tall)
    const float xlo = x0 + 0.5f, xhi = x0 + 31.5f;
    const float ylo = y0 + 0.5f, yhi = y0 + 7.5f;

    // phase A: each wave owns 256 gaussians, processed in 4 ordered rounds of 64
    int cnt = 0;
    for (int r = 0; r < 4; ++r) {
        const int n = (w << 8) + (r << 6) + lane;
        const float4 cu = cull[n];
        const float nx = fminf(fmaxf(cu.x, xlo), xhi);
        const float ny = fminf(fmaxf(cu.y, ylo), yhi);
        const float ddx = cu.x - nx, ddy = cu.y - ny;
        const bool live = (ddx*ddx + ddy*ddy) <= cu.z;   // r2 = -1 kills dead ones
        const unsigned long long m = __ballot(live);
        if (live) {
            const int pos = cnt + __popcll(m & ((1ull << lane) - 1ull));
            s_ids[w][pos] = (unsigned short)n;
        }
        cnt += __popcll(m);
    }
    if (lane == 0) s_cnt[w] = cnt;
    __syncthreads();

    // merge the 4 per-wave lists in wave order -> globally ascending ids
    const int c0 = s_cnt[0], c1 = s_cnt[1], c2 = s_cnt[2], c3 = s_cnt[3];
    const int offw = (w > 0 ? c0 : 0) + (w > 1 ? c1 : 0) + (w > 2 ? c2 : 0);
    const int myc = s_cnt[w];
    for (int i = lane; i < myc; i += 64) s_list[offw + i] = s_ids[w][i];
    __syncthreads();
    const int total = __builtin_amdgcn_readfirstlane(c0 + c1 + c2 + c3);

    // phase B: per-pixel accumulation
    const int tx = tid & 31, ty = tid >> 5;
    const float px = x0 + tx + 0.5f;
    const float py = y0 + ty + 0.5f;

    float acc[NC];
    #pragma unroll
    for (int c = 0; c < NC; ++c) acc[c] = 0.f;

    for (int i = 0; i < total; ++i) {
        const int n = __builtin_amdgcn_readfirstlane((int)s_list[i]);
        const float4 cu = cull[n];   // wave-uniform -> scalar loads
        const float4 cf = coef[n];
        const float4 gb = gab[n];
        const float2 wk = wts[n];

        const float dx = cu.x - px, dy = cu.y - py;
        const float sig = 0.5f * (cf.x*dx*dx + cf.z*dy*dy) + cf.y*dx*dy;
        const float a   = __expf(-sig) * cu.w;
        const float mfac = 1.f + wk.x * __cosf(gb.x*dx + gb.y*dy)
                               + wk.y * __cosf(gb.z*dx + gb.w*dy);
        const float wgt = a * mfac;

        const float* fp = feats + (n << 6);
        #pragma unroll
        for (int c = 0; c < NC; ++c) acc[c] = fmaf(wgt, fp[c], acc[c]);
    }

    // store: out[(c, y, x)] with p = y*256 + x; lanes contiguous in x (128B rows)
    const int p = ((y0 + ty) << 8) + x0 + tx;
    #pragma unroll
    for (int c = 0; c < NC; ++c)
        out[(c << 16) + p] = fminf(fmaxf(acc[c], 0.f), 1.f);
}

// ---------------------------------------------------------------------------
extern "C" void kernel_launch(void* const* d_in, const int* in_sizes, int n_in,
                              void* d_out, int out_size, void* d_ws, size_t ws_size,
                              hipStream_t stream) {
    const float* xyz  = (const float*)d_in[0];
    const float* chol = (const float*)d_in[1];
    const float* opac = (const float*)d_in[2];
    const float* fdc  = (const float*)d_in[3];
    const float* gfrq = (const float*)d_in[4];
    const float* gwts = (const float*)d_in[5];

    char* ws = (char*)d_ws;
    // ws layout (needs 319488 B): feats 256KB | cull 16KB | coef 16KB | gab 16KB | wts 8KB
    float*  feats = (float*) (ws);
    float4* cull  = (float4*)(ws + 262144);
    float4* coef  = (float4*)(ws + 278528);
    float4* gab   = (float4*)(ws + 294912);
    float2* wtsp  = (float2*)(ws + 311296);

    prep_kernel<<<257, 256, 0, stream>>>(xyz, chol, opac, fdc, gfrq, gwts,
                                         feats, cull, coef, gab, wtsp);
    render_kernel<<<256, 256, 0, stream>>>(feats, cull, coef, gab, wtsp,
                                           (float*)d_out);
}